// Round 18
// baseline (16.827 us; speedup 1.0000x reference)
//
#include <hip/hip_runtime.h>
#include <hip/hip_bf16.h>

#define H 1024
#define B 128
#define MAGIC 0x5DEADBEEFCAFE123ULL

typedef unsigned short u16;
typedef unsigned int u32;
typedef unsigned long long u64;
typedef __attribute__((ext_vector_type(8))) short bf16x8;
typedef __attribute__((ext_vector_type(4))) float f32x4;

static __device__ inline u16 f2bf(float x) {
    __hip_bfloat16 h = __float2bfloat16(x);   // RTNE
    return __builtin_bit_cast(u16, h);
}
// device-scope (sc1) ws accesses: producer writes land at the shared LLC,
// consumer reads bypass the XCD-private L2 (proven correct+cheap in R17).
static __device__ inline void st64(u16* p, u64 v) {
    __hip_atomic_store((u64*)p, v, __ATOMIC_RELAXED, __HIP_MEMORY_SCOPE_AGENT);
}
static __device__ inline u64 ld64(const u16* p) {
    return __hip_atomic_load((const u64*)p, __ATOMIC_RELAXED, __HIP_MEMORY_SCOPE_AGENT);
}
static __device__ inline void st16(u16* p, u16 v) {
    __hip_atomic_store(p, v, __ATOMIC_RELAXED, __HIP_MEMORY_SCOPE_AGENT);
}

// ONE plain launch: 256 blocks x 512 threads.
// Phase A: block b computes U-rows 4b..4b+3 -> Q=expU/S in pack-of-4 layout
//   expUP4[k>>2][j][k&3] (sc1), plus a 512-elem slice of exp(A) (sc1), then
//   sets flags[b]=MAGIC (sc1, after barrier-drained stores).
// Spin: wait for all 256 flags (sc1 loads). Deadlock-free: every block
//   produces before consuming; 256 blocks <= 256 CUs all dispatch at once.
//   Correct for ANY initial ws state: poison -> wait; stale MAGIC -> data
//   at LLC is bit-identical by determinism.
// Phase B: R17's pure load+MFMA k2 (8 waves: kh 0..3 K-split, jh 0..1).
__global__ __launch_bounds__(512) void kall(const float* __restrict__ A,
                                            const float* __restrict__ U,
                                            u16* __restrict__ expUP4,
                                            u16* __restrict__ expA,
                                            u64* __restrict__ flags,
                                            float* __restrict__ out) {
    __shared__ u16 Le[4][1024];          // 8 KB  row-scaled expU staging
    __shared__ float part[8];            // per-wave row partials
    __shared__ float red[4][2][4][66];   // phase-B kh-reduce, 8.4 KB

    const int t = threadIdx.x, l = t & 63, w = t >> 6;
    const int bid = blockIdx.x;          // 0..255

    // ---------------- phase A ----------------
    {
        const int tr = t >> 7;           // row 0..3 (this block's k = 4*bid+tr)
        const int j8 = (t & 127) * 8;    // 8 consecutive j per thread
        const float* Ur = U + (size_t)(bid * 4 + tr) * H + j8;
        float4 u0 = *reinterpret_cast<const float4*>(Ur);
        float4 u1 = *reinterpret_cast<const float4*>(Ur + 4);
        float e0 = __expf(u0.x), e1 = __expf(u0.y), e2 = __expf(u0.z), e3 = __expf(u0.w);
        float e4 = __expf(u1.x), e5 = __expf(u1.y), e6 = __expf(u1.z), e7 = __expf(u1.w);
        float s = (e0 + e1 + e2 + e3) + (e4 + e5 + e6 + e7);
        #pragma unroll
        for (int off = 32; off > 0; off >>= 1) s += __shfl_xor(s, off, 64);
        if (l == 0) part[w] = s;
        __syncthreads();
        const float is = 1.0f / (part[tr * 2] + part[tr * 2 + 1]);
        ushort4 o0 = {f2bf(e0 * is), f2bf(e1 * is), f2bf(e2 * is), f2bf(e3 * is)};
        ushort4 o1 = {f2bf(e4 * is), f2bf(e5 * is), f2bf(e6 * is), f2bf(e7 * is)};
        *reinterpret_cast<ushort4*>(&Le[tr][j8])     = o0;
        *reinterpret_cast<ushort4*>(&Le[tr][j8 + 4]) = o1;
        __syncthreads();
        // pack-of-4 write-out: columns t and t+512
        #pragma unroll
        for (int m = 0; m < 2; ++m) {
            const int j = t + m * 512;
            const u64 v = (u64)Le[0][j] | ((u64)Le[1][j] << 16)
                        | ((u64)Le[2][j] << 32) | ((u64)Le[3][j] << 48);
            st64(expUP4 + ((size_t)bid * H + j) * 4, v);
        }
        // exp(A) slice: element bid*512 + t
        {
            const size_t off = (size_t)bid * 512 + t;
            st16(expA + off, f2bf(__expf(A[off])));
        }
        __syncthreads();                 // drains vmcnt(0) for the whole block
        if (t == 0)
            __hip_atomic_store(&flags[bid], (u64)MAGIC,
                               __ATOMIC_RELAXED, __HIP_MEMORY_SCOPE_AGENT);
    }

    // ---------------- spin ----------------
    if (t < 256) {
        while (__hip_atomic_load(&flags[t], __ATOMIC_RELAXED,
                                 __HIP_MEMORY_SCOPE_AGENT) != (u64)MAGIC)
            __builtin_amdgcn_s_sleep(1);
    }
    __syncthreads();
    asm volatile("" ::: "memory");       // no compile-time hoist above the spin

    // ---------------- phase B ----------------
    {
        const int jh = w & 1, kh = w >> 1;
        const int b0 = (bid & 7) * 16;
        const int j0 = (bid >> 3) * 32;
        const int colJ = j0 + jh * 16 + (l & 15);
        const int arow = b0 + (l & 15);
        const int kg   = l >> 4;         // 0..3

        f32x4 acc = {0.f, 0.f, 0.f, 0.f};
        #pragma unroll
        for (int s = 0; s < 8; ++s) {
            const int kk = s * 128 + kh * 32 + kg * 8;
            const u16* ap = expA + (size_t)arow * H + kk;
            const int kq = kk >> 2;
            const u64 alo = ld64(ap), ahi = ld64(ap + 4);
            const u64 blo = ld64(expUP4 + ((size_t)kq * H + colJ) * 4);
            const u64 bhi = ld64(expUP4 + ((size_t)(kq + 1) * H + colJ) * 4);
            uint4 aw = {(u32)alo, (u32)(alo >> 32), (u32)ahi, (u32)(ahi >> 32)};
            uint4 bw = {(u32)blo, (u32)(blo >> 32), (u32)bhi, (u32)(bhi >> 32)};
            acc = __builtin_amdgcn_mfma_f32_16x16x32_bf16(
                __builtin_bit_cast(bf16x8, aw), __builtin_bit_cast(bf16x8, bw),
                acc, 0, 0, 0);
        }

        #pragma unroll
        for (int r = 0; r < 4; ++r) red[kh][jh][r][l] = acc[r];
        __syncthreads();

        const int row = t >> 5, c = t & 31;
        const int jj = c >> 4, cc = c & 15;
        const int ll = (row >> 2) * 16 + cc, r = row & 3;
        const float v = red[0][jj][r][ll] + red[1][jj][r][ll]
                      + red[2][jj][r][ll] + red[3][jj][r][ll];
        out[(size_t)(b0 + row) * H + j0 + c] = __logf(v);
    }
}

extern "C" void kernel_launch(void* const* d_in, const int* in_sizes, int n_in,
                              void* d_out, int out_size, void* d_ws, size_t ws_size,
                              hipStream_t stream) {
    const float* A = (const float*)d_in[0];   // log_alpha (128 x 1024)
    const float* U = (const float*)d_in[1];   // unnormalized_tran (1024 x 1024)
    float* out = (float*)d_out;               // (128 x 1024) f32

    char* ws = (char*)d_ws;
    u16* expUP4 = (u16*)ws;                                       // 2 MB
    u16* expA   = (u16*)(ws + (size_t)2 * 1024 * 1024);           // 256 KB
    u64* flags  = (u64*)(ws + (size_t)2 * 1024 * 1024 + 256 * 1024); // 2 KB

    kall<<<256, 512, 0, stream>>>(A, U, expUP4, expA, flags, out);
}

// Round 19
// 16.168 us; speedup vs baseline: 1.0407x; 1.0407x over previous
//
#include <hip/hip_runtime.h>
#include <hip/hip_bf16.h>

#define H 1024
#define B 128

typedef unsigned short u16;
typedef unsigned int u32;
typedef unsigned long long u64;
typedef __attribute__((ext_vector_type(8))) short bf16x8;
typedef __attribute__((ext_vector_type(4))) float f32x4;

static __device__ inline u16 f2bf(float x) {
    __hip_bfloat16 h = __float2bfloat16(x);   // RTNE
    return __builtin_bit_cast(u16, h);
}
// Only the tiny expAS handoff is device-scope (sc1) — R17-proven safe under
// graph replay. Everything else (U, A, out) is normal cached traffic.
static __device__ inline void st32a(u32* p, u32 v) {
    __hip_atomic_store(p, v, __ATOMIC_RELAXED, __HIP_MEMORY_SCOPE_AGENT);
}
static __device__ inline u64 ld64a(const u16* p) {
    return __hip_atomic_load((const u64*)p, __ATOMIC_RELAXED, __HIP_MEMORY_SCOPE_AGENT);
}

// ---- k1: 256 blocks x 256 threads. Block owns k-rows 4blk..4blk+3. --------
// Wave w: invS = 1/sum_j exp(U[4blk+w][j]).
// Then expAS[b][k] = bf16(exp(A[b][k]) * invS[k]) for the block's 4 k, all b.
// Handoff total: 256 KB sc1. No expU materialization, no LDS transpose.
__global__ __launch_bounds__(256) void k1(const float* __restrict__ A,
                                          const float* __restrict__ U,
                                          u16* __restrict__ expAS) {
    const int t = threadIdx.x, w = t >> 6, l = t & 63;
    const int blk = blockIdx.x;
    __shared__ float part[4];   // invS of the block's 4 rows
    {
        const float* Ur = U + (size_t)(blk * 4 + w) * H;
        float s = 0.f;
        #pragma unroll
        for (int c = 0; c < 4; ++c) {
            float4 u4 = *reinterpret_cast<const float4*>(Ur + c * 256 + l * 4);
            s += __expf(u4.x) + __expf(u4.y) + __expf(u4.z) + __expf(u4.w);
        }
        #pragma unroll
        for (int off = 32; off > 0; off >>= 1) s += __shfl_xor(s, off, 64);
        if (l == 0) part[w] = 1.0f / s;
    }
    __syncthreads();
    {
        const int b  = t & 127;          // output row
        const int kp = t >> 7;           // 0..1 -> k pair
        const int k  = blk * 4 + kp * 2;
        float2 a2 = *reinterpret_cast<const float2*>(A + (size_t)b * H + k);
        const u32 v = (u32)f2bf(__expf(a2.x) * part[kp * 2])
                    | ((u32)f2bf(__expf(a2.y) * part[kp * 2 + 1]) << 16);
        st32a((u32*)(expAS + (size_t)b * H + k), v);
    }
}

// ---- k2: out[b][j] = log( sum_k expAS[b][k] * exp(U[k][j]) ) --------------
// grid (32 jt, 8 bt) x 512 threads = 8 waves: kh 0..3 (K-split), jh 0..1.
// A-fragments: sc1 b64 pairs (8 MB total). B-fragments: recomputed from U
// with normal cached loads (same-jt blocks are co-XCD -> L2 reuse).
__global__ __launch_bounds__(512) void k2(const u16* __restrict__ expAS,
                                          const float* __restrict__ U,
                                          float* __restrict__ out) {
    __shared__ float red[4][2][4][66];   // [kh][jh][r][lane], pad 66
    const int t = threadIdx.x, l = t & 63, w = t >> 6;
    const int jh = w & 1, kh = w >> 1;
    const int j0 = blockIdx.x * 32;      // x = jt so same-jt lands co-XCD
    const int b0 = blockIdx.y * 16;
    const int colJ = j0 + jh * 16 + (l & 15);
    const int arow = b0 + (l & 15);
    const int kg   = l >> 4;             // 0..3

    f32x4 acc = {0.f, 0.f, 0.f, 0.f};
    #pragma unroll
    for (int s = 0; s < 8; ++s) {
        const int kk = s * 128 + kh * 32 + kg * 8;
        const u16* ap = expAS + (size_t)arow * H + kk;
        const u64 alo = ld64a(ap), ahi = ld64a(ap + 4);
        const float* up = U + (size_t)kk * H + colJ;
        const float e0 = __expf(up[0 * H]), e1 = __expf(up[1 * H]);
        const float e2 = __expf(up[2 * H]), e3 = __expf(up[3 * H]);
        const float e4 = __expf(up[4 * H]), e5 = __expf(up[5 * H]);
        const float e6 = __expf(up[6 * H]), e7 = __expf(up[7 * H]);
        uint4 bw;
        bw.x = (u32)f2bf(e0) | ((u32)f2bf(e1) << 16);
        bw.y = (u32)f2bf(e2) | ((u32)f2bf(e3) << 16);
        bw.z = (u32)f2bf(e4) | ((u32)f2bf(e5) << 16);
        bw.w = (u32)f2bf(e6) | ((u32)f2bf(e7) << 16);
        uint4 aw = {(u32)alo, (u32)(alo >> 32), (u32)ahi, (u32)(ahi >> 32)};
        acc = __builtin_amdgcn_mfma_f32_16x16x32_bf16(
            __builtin_bit_cast(bf16x8, aw), __builtin_bit_cast(bf16x8, bw),
            acc, 0, 0, 0);
    }

    #pragma unroll
    for (int r = 0; r < 4; ++r) red[kh][jh][r][l] = acc[r];
    __syncthreads();

    // one output per thread: row = t>>5 (0..15), c = t&31
    const int row = t >> 5, c = t & 31;
    const int jj = c >> 4, cc = c & 15;
    const int ll = (row >> 2) * 16 + cc, r = row & 3;
    const float v = red[0][jj][r][ll] + red[1][jj][r][ll]
                  + red[2][jj][r][ll] + red[3][jj][r][ll];
    out[(size_t)(b0 + row) * H + j0 + c] = __logf(v);
}

extern "C" void kernel_launch(void* const* d_in, const int* in_sizes, int n_in,
                              void* d_out, int out_size, void* d_ws, size_t ws_size,
                              hipStream_t stream) {
    const float* A = (const float*)d_in[0];   // log_alpha (128 x 1024)
    const float* U = (const float*)d_in[1];   // unnormalized_tran (1024 x 1024)
    float* out = (float*)d_out;               // (128 x 1024) f32

    u16* expAS = (u16*)d_ws;                  // 256 KB handoff (the ONLY ws)

    k1<<<256, 256, 0, stream>>>(A, U, expAS);
    dim3 g(H / 32, B / 16);                   // (32, 8) = 256 blocks
    k2<<<g, 512, 0, stream>>>(expAS, U, out);
}